// Round 5
// baseline (253.353 us; speedup 1.0000x reference)
//
#include <hip/hip_runtime.h>
#include <math.h>

#define B_ 8
#define T_ 1000
#define C_ 8
#define F_ 257
#define A_ 320

// ---------------- Kernel 1: (B,T,C,F) -> (B,F,C,T) interleaved float2 ----------
__global__ __launch_bounds__(256) void k_transpose(
    const float* __restrict__ dre, const float* __restrict__ dim_,
    float2* __restrict__ xt) {
  __shared__ float2 tile[32][33];
  int bc = blockIdx.z;
  int b = bc >> 3, c = bc & 7;
  int t0 = blockIdx.y * 32, f0 = blockIdx.x * 32;
  int tx = threadIdx.x, ty = threadIdx.y;
#pragma unroll
  for (int j = 0; j < 4; ++j) {
    int t = t0 + ty + j * 8, f = f0 + tx;
    if (t < T_ && f < F_) {
      size_t idx = ((size_t)(b * T_ + t) * C_ + c) * F_ + f;
      tile[ty + j * 8][tx] = make_float2(dre[idx], dim_[idx]);
    }
  }
  __syncthreads();
#pragma unroll
  for (int j = 0; j < 4; ++j) {
    int f = f0 + ty + j * 8, t = t0 + tx;
    if (t < T_ && f < F_) {
      xt[((size_t)(b * F_ + f) * C_ + c) * T_ + t] = tile[tx][ty + j * 8];
    }
  }
}

// ---------------- Kernel 2: PSDs + attention features — NO LDS, NO BARRIERS ----
// All 8 lane-groups read the same x stream through L1 (xt is L3-resident:
// r3 FETCH_SIZE == mask bytes only). Manual 2x unroll double-buffers loads
// in registers; waves free-run (no vmcnt-drain points).
#define PSD_STEP(X, XC, MS, MN) do {                                  \
    ss += (MS); sn += (MN);                                           \
    _Pragma("unroll")                                                 \
    for (int e = 0; e < C_; ++e) {                                    \
      float tre = (XC).x * X[e].x + (XC).y * X[e].y;                  \
      float tim = (XC).y * X[e].x - (XC).x * X[e].y;                  \
      as_[e].x += (MS) * tre; as_[e].y += (MS) * tim;                 \
      an_[e].x += (MN) * tre; an_[e].y += (MN) * tim;                 \
    } } while (0)

__global__ __launch_bounds__(256) void k_psd(
    const float2* __restrict__ xt,
    const float* __restrict__ ms, const float* __restrict__ mn,
    float2* __restrict__ psd_s, float2* __restrict__ psd_n,
    float* __restrict__ feat) {
  int bf = blockIdx.x;            // b*F + f
  int b = bf / F_;
  int f = bf - b * F_;
  int tid = threadIdx.x;
  int g = tid >> 5;               // channel (PSD row) owned by this 32-lane group
  int lane = tid & 31;

  const float2* xg  = xt + (size_t)bf * (C_ * T_);      // [c*T_ + t]
  const float2* xgc = xg + (size_t)g * T_;              // own channel row
  const float* msg = ms + (size_t)bf * (C_ * T_) + g * T_;
  const float* mng = mn + (size_t)bf * (C_ * T_) + g * T_;

  float2 as_[C_], an_[C_];
#pragma unroll
  for (int e = 0; e < C_; ++e) { as_[e] = make_float2(0.f, 0.f); an_[e] = make_float2(0.f, 0.f); }
  float ss = 0.f, sn = 0.f;

  float2 xa[C_], xb[C_];
  float2 xca, xcb;
  float msa, mna, msb, mnb;

  // prologue: i=0 into the a-buffer
  {
    int t = lane;
#pragma unroll
    for (int c = 0; c < C_; ++c) xa[c] = xg[c * T_ + t];
    xca = xgc[t];
    msa = msg[t]; mna = mng[t];
  }

  // T=1000 = 31 full 32-wide steps + tail (lanes 0..7 at t=992+lane).
  // Pairs (i, i+1): load b(i+1); compute a(i); load a(i+2); compute b(i+1).
  for (int i = 0; i < 30; i += 2) {
    int t1 = lane + (i + 1) * 32;
#pragma unroll
    for (int c = 0; c < C_; ++c) xb[c] = xg[c * T_ + t1];
    xcb = xgc[t1];
    msb = msg[t1]; mnb = mng[t1];

    PSD_STEP(xa, xca, msa, mna);

    int t2 = lane + (i + 2) * 32;
#pragma unroll
    for (int c = 0; c < C_; ++c) xa[c] = xg[c * T_ + t2];
    xca = xgc[t2];
    msa = msg[t2]; mna = mng[t2];

    PSD_STEP(xb, xcb, msb, mnb);
  }
  // i=30 (a-buffer holds it) + tail i=31 for lanes 0..7
  bool tv = lane < 8;             // t = 992 + lane < 1000
  if (tv) {
    int t31 = 992 + lane;
#pragma unroll
    for (int c = 0; c < C_; ++c) xb[c] = xg[c * T_ + t31];
    xcb = xgc[t31];
    msb = msg[t31]; mnb = mng[t31];
  }
  PSD_STEP(xa, xca, msa, mna);
  if (tv) PSD_STEP(xb, xcb, msb, mnb);

  // reduce across the 32 lanes of the group
#pragma unroll
  for (int s = 16; s >= 1; s >>= 1) {
    ss += __shfl_xor(ss, s);
    sn += __shfl_xor(sn, s);
#pragma unroll
    for (int e = 0; e < C_; ++e) {
      as_[e].x += __shfl_xor(as_[e].x, s);
      as_[e].y += __shfl_xor(as_[e].y, s);
      an_[e].x += __shfl_xor(an_[e].x, s);
      an_[e].y += __shfl_xor(an_[e].y, s);
    }
  }

  if (lane == 0) {
    float inv_s = 1.f / (ss + 1e-6f);
    float inv_n = 1.f / (sn + 1e-6f);
    float2* ps = psd_s + (size_t)bf * (C_ * C_) + g * C_;
    float2* pn = psd_n + (size_t)bf * (C_ * C_) + g * C_;
    float sr = 0.f, si = 0.f;
#pragma unroll
    for (int e = 0; e < C_; ++e) {
      float2 vs = make_float2(as_[e].x * inv_s, as_[e].y * inv_s);
      float2 vn = make_float2(an_[e].x * inv_n, an_[e].y * inv_n);
      ps[e] = vs; pn[e] = vn;
      if (e != g) { sr += vs.x; si += vs.y; }
    }
    sr *= (1.f / 7.f); si *= (1.f / 7.f);
    feat[(b * C_ + g) * F_ + f] = sqrtf(sr * sr + si * si);
  }
}

// ---------------- Kernel 3: attention MLP partial logits ----------------------
// grid (B, 5), block 64. Each block: 64 a-rows. b_gvec dropped (softmax-invariant).
__global__ __launch_bounds__(64) void k_attn(
    const float* __restrict__ feat, const float* __restrict__ wmlp,
    const float* __restrict__ bmlp, const float* __restrict__ wgv,
    float* __restrict__ e_part) {
  __shared__ float fl[C_ * F_];   // 8224 B
  int b = blockIdx.x, p = blockIdx.y;
  int tid = threadIdx.x;
  for (int i = tid; i < C_ * F_; i += 64) fl[i] = feat[b * C_ * F_ + i];
  __syncthreads();

  int a = p * 64 + tid;           // A = 320 = 5*64 exactly
  const float* wr = wmlp + a * F_;
  float acc[C_];
  float bm = bmlp[a];
#pragma unroll
  for (int c = 0; c < C_; ++c) acc[c] = bm;
  for (int k = 0; k < F_; ++k) {
    float w = wr[k];
#pragma unroll
    for (int c = 0; c < C_; ++c) acc[c] += w * fl[c * F_ + k];
  }
  float wg = wgv[a];
  float ec[C_];
#pragma unroll
  for (int c = 0; c < C_; ++c) ec[c] = wg * tanhf(acc[c]);

#pragma unroll
  for (int s = 32; s >= 1; s >>= 1) {
#pragma unroll
    for (int c = 0; c < C_; ++c) ec[c] += __shfl_xor(ec[c], s);
  }
  if (tid == 0) {
#pragma unroll
    for (int c = 0; c < C_; ++c) e_part[(b * 5 + p) * C_ + c] = ec[c];
  }
}

// ---------------- Kernel 4: softmax + tik-reg + 8x8 complex solve + ws ---------
__global__ __launch_bounds__(64) void k_solve(
    const float2* __restrict__ psd_s, const float2* __restrict__ psd_n,
    const float* __restrict__ e_part, float2* __restrict__ wsv) {
  int bf = blockIdx.x;
  int b = bf / F_;
  int l = threadIdx.x;
  int r = l >> 3, q = l & 7;

  // softmax over channels (each 8-lane subgroup spans q=0..7)
  float e_c = 0.f;
#pragma unroll
  for (int p = 0; p < 5; ++p) e_c += e_part[(b * 5 + p) * C_ + q];
  e_c *= 2.0f;  // SCALING
  float mx = e_c;
#pragma unroll
  for (int s = 4; s >= 1; s >>= 1) mx = fmaxf(mx, __shfl_xor(mx, s));
  float ex = expf(e_c - mx);
  float sm = ex;
#pragma unroll
  for (int s = 4; s >= 1; s >>= 1) sm += __shfl_xor(sm, s);
  float uq = ex / sm;

  float2 M = psd_n[(size_t)bf * 64 + l];
  float2 R = psd_s[(size_t)bf * 64 + l];

  // trace(psd_n).real
  float td = (r == q) ? M.x : 0.f;
#pragma unroll
  for (int s = 32; s >= 1; s >>= 1) td += __shfl_xor(td, s);
  if (r == q) M.x += 1e-7f * (td * 0.125f) + 1e-8f;

  // Gauss-Jordan: M X = R  ->  R becomes X
#pragma unroll
  for (int k = 0; k < 8; ++k) {
    float pr = __shfl(M.x, k * 9), pi = __shfl(M.y, k * 9);
    float den = pr * pr + pi * pi;
    float ir = pr / den, ii = -pi / den;          // 1/pivot
    float mkr = __shfl(M.x, k * 8 + q), mki = __shfl(M.y, k * 8 + q);
    float rkr = __shfl(R.x, k * 8 + q), rki = __shfl(R.y, k * 8 + q);
    float gr = __shfl(M.x, r * 8 + k), gi = __shfl(M.y, r * 8 + k);
    if (r == k) {
      float nmr = M.x * ir - M.y * ii, nmi = M.x * ii + M.y * ir;
      float nrr = R.x * ir - R.y * ii, nri = R.x * ii + R.y * ir;
      M = make_float2(nmr, nmi); R = make_float2(nrr, nri);
    } else {
      float fr = gr * ir - gi * ii, fi = gr * ii + gi * ir;   // M[r,k]/pivot
      M.x -= fr * mkr - fi * mki; M.y -= fr * mki + fi * mkr;
      R.x -= fr * rkr - fi * rki; R.y -= fr * rki + fi * rkr;
    }
  }

  // trace(X), normalize, apply u
  float trr = (r == q) ? R.x : 0.f, tri = (r == q) ? R.y : 0.f;
#pragma unroll
  for (int s = 32; s >= 1; s >>= 1) { trr += __shfl_xor(trr, s); tri += __shfl_xor(tri, s); }
  trr += 1e-6f;  // + EPS (real)
  float den = trr * trr + tri * tri;
  float ir = trr / den, ii = -tri / den;
  float wr_ = R.x * ir - R.y * ii;   // ws_mat[r][q]
  float wi_ = R.x * ii + R.y * ir;
  float vr = wr_ * uq, vi = wi_ * uq;
#pragma unroll
  for (int s = 4; s >= 1; s >>= 1) { vr += __shfl_xor(vr, s); vi += __shfl_xor(vi, s); }
  if (q == 0) wsv[(size_t)bf * C_ + r] = make_float2(vr, vi);
}

// ---------------- Kernel 5: enhanced[b,t,f] = sum_c conj(ws) * x ----------------
__global__ __launch_bounds__(256) void k_bf(
    const float* __restrict__ dre, const float* __restrict__ dim_,
    const float2* __restrict__ wsv, float2* __restrict__ out) {
  __shared__ float2 wl[C_][F_];
  int blk = blockIdx.x;
  int b = blk / 125;
  int t0 = (blk - b * 125) * 8;
  int tid = threadIdx.x;
  // wsv layout [b][f][c] -> wl[c][f]
  for (int i = tid; i < C_ * F_; i += 256) {
    int f = i >> 3, c = i & 7;
    wl[c][f] = wsv[(size_t)b * (F_ * C_) + i];
  }
  __syncthreads();

  for (int dt = 0; dt < 8; ++dt) {
    int t = t0 + dt;
    const float* pr = dre + (size_t)(b * T_ + t) * (C_ * F_);
    const float* pi_ = dim_ + (size_t)(b * T_ + t) * (C_ * F_);
    for (int f = tid; f < F_; f += 256) {
      float ar = 0.f, ai = 0.f;
#pragma unroll
      for (int c = 0; c < C_; ++c) {
        float xr = pr[c * F_ + f], xi = pi_[c * F_ + f];
        float2 w = wl[c][f];
        ar += w.x * xr + w.y * xi;   // conj(w)*x
        ai += w.x * xi - w.y * xr;
      }
      out[(size_t)(b * T_ + t) * F_ + f] = make_float2(ar, ai);
    }
  }
}

extern "C" void kernel_launch(void* const* d_in, const int* in_sizes, int n_in,
                              void* d_out, int out_size, void* d_ws, size_t ws_size,
                              hipStream_t stream) {
  const float* dre = (const float*)d_in[0];
  const float* dim_ = (const float*)d_in[1];
  const float* ms = (const float*)d_in[2];
  const float* mn = (const float*)d_in[3];
  const float* wmlp = (const float*)d_in[4];
  const float* bmlp = (const float*)d_in[5];
  const float* wgv = (const float*)d_in[6];
  // d_in[7] = b_gvec: constant shift, cancels in softmax — unused.

  char* ws = (char*)d_ws;
  float2* xt    = (float2*)(ws);                    // B*F*C*T float2 = 131,584,000 B
  float2* psd_s = (float2*)(ws + 131584000);        // 1,052,672 B
  float2* psd_n = (float2*)(ws + 132636672);        // 1,052,672 B
  float*  feat  = (float*) (ws + 133689344);        // 65,792 B
  float*  e_prt = (float*) (ws + 133755136);        // 8*5*8*4 = 1,280 B
  float2* wsv   = (float2*)(ws + 133756416);        // 131,584 B

  dim3 g1(9, 32, B_ * C_), b1(32, 8, 1);
  k_transpose<<<g1, b1, 0, stream>>>(dre, dim_, xt);
  k_psd<<<B_ * F_, 256, 0, stream>>>(xt, ms, mn, psd_s, psd_n, feat);
  dim3 ga(B_, 5, 1);
  k_attn<<<ga, 64, 0, stream>>>(feat, wmlp, bmlp, wgv, e_prt);
  k_solve<<<B_ * F_, 64, 0, stream>>>(psd_s, psd_n, e_prt, wsv);
  k_bf<<<B_ * 125, 256, 0, stream>>>(dre, dim_, wsv, (float2*)d_out);
}

// Round 6
// 232.557 us; speedup vs baseline: 1.0894x; 1.0894x over previous
//
#include <hip/hip_runtime.h>
#include <math.h>

#define B_ 8
#define T_ 1000
#define C_ 8
#define F_ 257
#define A_ 320
#define THALF_ 500

// ---------------- Kernel 1: (B,T,C,F) -> (B,F,C,T) interleaved float2 ----------
__global__ __launch_bounds__(256) void k_transpose(
    const float* __restrict__ dre, const float* __restrict__ dim_,
    float2* __restrict__ xt) {
  __shared__ float2 tile[32][33];
  int bc = blockIdx.z;
  int b = bc >> 3, c = bc & 7;
  int t0 = blockIdx.y * 32, f0 = blockIdx.x * 32;
  int tx = threadIdx.x, ty = threadIdx.y;
#pragma unroll
  for (int j = 0; j < 4; ++j) {
    int t = t0 + ty + j * 8, f = f0 + tx;
    if (t < T_ && f < F_) {
      size_t idx = ((size_t)(b * T_ + t) * C_ + c) * F_ + f;
      tile[ty + j * 8][tx] = make_float2(dre[idx], dim_[idx]);
    }
  }
  __syncthreads();
#pragma unroll
  for (int j = 0; j < 4; ++j) {
    int f = f0 + ty + j * 8, t = t0 + tx;
    if (t < T_ && f < F_) {
      xt[((size_t)(b * F_ + f) * C_ + c) * T_ + t] = tile[tx][ty + j * 8];
    }
  }
}

// ---------------- Kernel 2: partial PSDs — wave-per-(bf,half), shfl broadcast --
// No LDS, no barriers. Lane = (c = l>>3, tl = l&7); per step 3 coalesced loads;
// cross-channel x via __shfl (in-register broadcast). 1-ahead register dbuf.
// Writes UNNORMALIZED partial sums + mask partial sums; halves combined later.
__global__ __launch_bounds__(256) void k_psd(
    const float2* __restrict__ xt,
    const float* __restrict__ ms, const float* __restrict__ mn,
    float2* __restrict__ psp, float2* __restrict__ pnp,
    float* __restrict__ msum, float* __restrict__ nsum) {
  int wid = blockIdx.x * 4 + (threadIdx.x >> 6);   // 0..4111
  int bf = wid >> 1, half = wid & 1;
  int l = threadIdx.x & 63;
  int c = l >> 3, tl = l & 7;

  const float2* xr = xt + (size_t)bf * (C_ * T_) + c * T_;
  const float*  mr = ms + (size_t)bf * (C_ * T_) + c * T_;
  const float*  nr = mn + (size_t)bf * (C_ * T_) + c * T_;
  int t0 = half * THALF_, tend = t0 + THALF_;

  float2 as_[C_], an_[C_];
#pragma unroll
  for (int e = 0; e < C_; ++e) { as_[e] = make_float2(0.f, 0.f); an_[e] = make_float2(0.f, 0.f); }
  float ss = 0.f, sn = 0.f;

  int t = t0 + tl;
  float2 xva = xr[t];
  float msa = mr[t], mna = nr[t];

  // 500 = 8*62.5 -> 63 steps, last step valid only for tl<4 (zero-padded).
  for (int i = 0; i < 63; ++i) {
    int tn = t + 8;
    float2 xvb = make_float2(0.f, 0.f);
    float msb = 0.f, mnb = 0.f;
    if (tn < tend) { xvb = xr[tn]; msb = mr[tn]; mnb = nr[tn]; }

    ss += msa; sn += mna;
#pragma unroll
    for (int e = 0; e < C_; ++e) {
      float xex = __shfl(xva.x, e * 8 + tl);
      float xey = __shfl(xva.y, e * 8 + tl);
      float tre = xva.x * xex + xva.y * xey;   // x_c * conj(x_e) .re
      float tim = xva.y * xex - xva.x * xey;   // .im
      as_[e].x += msa * tre; as_[e].y += msa * tim;
      an_[e].x += mna * tre; an_[e].y += mna * tim;
    }
    xva = xvb; msa = msb; mna = mnb;
    t = tn;
  }

  // reduce over the 8 t-slot lanes within each channel group (xor<8 stays in group)
#pragma unroll
  for (int s = 4; s >= 1; s >>= 1) {
    ss += __shfl_xor(ss, s);
    sn += __shfl_xor(sn, s);
#pragma unroll
    for (int e = 0; e < C_; ++e) {
      as_[e].x += __shfl_xor(as_[e].x, s);
      as_[e].y += __shfl_xor(as_[e].y, s);
      an_[e].x += __shfl_xor(an_[e].x, s);
      an_[e].y += __shfl_xor(an_[e].y, s);
    }
  }

  if (tl == 0) {
    size_t base = ((size_t)bf * 2 + half) * 64 + c * 8;
#pragma unroll
    for (int e = 0; e < C_; ++e) { psp[base + e] = as_[e]; pnp[base + e] = an_[e]; }
    msum[((size_t)bf * 2 + half) * 8 + c] = ss;
    nsum[((size_t)bf * 2 + half) * 8 + c] = sn;
  }
}

// ---------------- Kernel 2b: combine halves -> attention features --------------
__global__ __launch_bounds__(64) void k_comb(
    const float2* __restrict__ psp, const float* __restrict__ msum,
    float* __restrict__ feat) {
  int bf = blockIdx.x;
  int b = bf / F_;
  int f = bf - b * F_;
  int l = threadIdx.x;
  int c = l >> 3, e = l & 7;

  float2 s0 = psp[(size_t)bf * 128 + l];
  float2 s1 = psp[(size_t)bf * 128 + 64 + l];
  float ssum = msum[bf * 16 + c] + msum[bf * 16 + 8 + c];
  float inv = 1.f / (ssum + 1e-6f);
  float fr = (e == c) ? 0.f : (s0.x + s1.x) * inv;
  float fi = (e == c) ? 0.f : (s0.y + s1.y) * inv;
#pragma unroll
  for (int s = 4; s >= 1; s >>= 1) { fr += __shfl_xor(fr, s); fi += __shfl_xor(fi, s); }
  if (e == 0) {
    fr *= (1.f / 7.f); fi *= (1.f / 7.f);
    feat[(b * C_ + c) * F_ + f] = sqrtf(fr * fr + fi * fi);
  }
}

// ---------------- Kernel 3: attention MLP partial logits ----------------------
__global__ __launch_bounds__(64) void k_attn(
    const float* __restrict__ feat, const float* __restrict__ wmlp,
    const float* __restrict__ bmlp, const float* __restrict__ wgv,
    float* __restrict__ e_part) {
  __shared__ float fl[C_ * F_];   // 8224 B
  int b = blockIdx.x, p = blockIdx.y;
  int tid = threadIdx.x;
  for (int i = tid; i < C_ * F_; i += 64) fl[i] = feat[b * C_ * F_ + i];
  __syncthreads();

  int a = p * 64 + tid;           // A = 320 = 5*64 exactly
  const float* wr = wmlp + a * F_;
  float acc[C_];
  float bm = bmlp[a];
#pragma unroll
  for (int c = 0; c < C_; ++c) acc[c] = bm;
  for (int k = 0; k < F_; ++k) {
    float w = wr[k];
#pragma unroll
    for (int c = 0; c < C_; ++c) acc[c] += w * fl[c * F_ + k];
  }
  float wg = wgv[a];
  float ec[C_];
#pragma unroll
  for (int c = 0; c < C_; ++c) ec[c] = wg * tanhf(acc[c]);

#pragma unroll
  for (int s = 32; s >= 1; s >>= 1) {
#pragma unroll
    for (int c = 0; c < C_; ++c) ec[c] += __shfl_xor(ec[c], s);
  }
  if (tid == 0) {
#pragma unroll
    for (int c = 0; c < C_; ++c) e_part[(b * 5 + p) * C_ + c] = ec[c];
  }
}

// ---------------- Kernel 4: softmax + combine + tik-reg + solve + ws -----------
__global__ __launch_bounds__(64) void k_solve(
    const float2* __restrict__ psp, const float2* __restrict__ pnp,
    const float* __restrict__ msum, const float* __restrict__ nsum,
    const float* __restrict__ e_part, float2* __restrict__ wsv) {
  int bf = blockIdx.x;
  int b = bf / F_;
  int l = threadIdx.x;
  int r = l >> 3, q = l & 7;

  // softmax over channels (each 8-lane subgroup spans q=0..7)
  float e_c = 0.f;
#pragma unroll
  for (int p = 0; p < 5; ++p) e_c += e_part[(b * 5 + p) * C_ + q];
  e_c *= 2.0f;  // SCALING
  float mx = e_c;
#pragma unroll
  for (int s = 4; s >= 1; s >>= 1) mx = fmaxf(mx, __shfl_xor(mx, s));
  float ex = expf(e_c - mx);
  float sm = ex;
#pragma unroll
  for (int s = 4; s >= 1; s >>= 1) sm += __shfl_xor(sm, s);
  float uq = ex / sm;

  // combine halves + per-row mask normalization
  float2 M0 = pnp[(size_t)bf * 128 + l];
  float2 M1 = pnp[(size_t)bf * 128 + 64 + l];
  float2 R0 = psp[(size_t)bf * 128 + l];
  float2 R1 = psp[(size_t)bf * 128 + 64 + l];
  float nsr = nsum[bf * 16 + r] + nsum[bf * 16 + 8 + r];
  float msr = msum[bf * 16 + r] + msum[bf * 16 + 8 + r];
  float invn = 1.f / (nsr + 1e-6f);
  float invm = 1.f / (msr + 1e-6f);
  float2 M = make_float2((M0.x + M1.x) * invn, (M0.y + M1.y) * invn);
  float2 R = make_float2((R0.x + R1.x) * invm, (R0.y + R1.y) * invm);

  // trace(psd_n).real
  float td = (r == q) ? M.x : 0.f;
#pragma unroll
  for (int s = 32; s >= 1; s >>= 1) td += __shfl_xor(td, s);
  if (r == q) M.x += 1e-7f * (td * 0.125f) + 1e-8f;

  // Gauss-Jordan: M X = R  ->  R becomes X
#pragma unroll
  for (int k = 0; k < 8; ++k) {
    float pr = __shfl(M.x, k * 9), pi = __shfl(M.y, k * 9);
    float den = pr * pr + pi * pi;
    float ir = pr / den, ii = -pi / den;          // 1/pivot
    float mkr = __shfl(M.x, k * 8 + q), mki = __shfl(M.y, k * 8 + q);
    float rkr = __shfl(R.x, k * 8 + q), rki = __shfl(R.y, k * 8 + q);
    float gr = __shfl(M.x, r * 8 + k), gi = __shfl(M.y, r * 8 + k);
    if (r == k) {
      float nmr = M.x * ir - M.y * ii, nmi = M.x * ii + M.y * ir;
      float nrr = R.x * ir - R.y * ii, nri = R.x * ii + R.y * ir;
      M = make_float2(nmr, nmi); R = make_float2(nrr, nri);
    } else {
      float fr = gr * ir - gi * ii, fi = gr * ii + gi * ir;   // M[r,k]/pivot
      M.x -= fr * mkr - fi * mki; M.y -= fr * mki + fi * mkr;
      R.x -= fr * rkr - fi * rki; R.y -= fr * rki + fi * rkr;
    }
  }

  // trace(X), normalize, apply u
  float trr = (r == q) ? R.x : 0.f, tri = (r == q) ? R.y : 0.f;
#pragma unroll
  for (int s = 32; s >= 1; s >>= 1) { trr += __shfl_xor(trr, s); tri += __shfl_xor(tri, s); }
  trr += 1e-6f;  // + EPS (real)
  float den = trr * trr + tri * tri;
  float ir = trr / den, ii = -tri / den;
  float wr_ = R.x * ir - R.y * ii;   // ws_mat[r][q]
  float wi_ = R.x * ii + R.y * ir;
  float vr = wr_ * uq, vi = wi_ * uq;
#pragma unroll
  for (int s = 4; s >= 1; s >>= 1) { vr += __shfl_xor(vr, s); vi += __shfl_xor(vi, s); }
  if (q == 0) wsv[(size_t)bf * C_ + r] = make_float2(vr, vi);
}

// ---------------- Kernel 5: enhanced[b,t,f] = sum_c conj(ws) * x ----------------
__global__ __launch_bounds__(256) void k_bf(
    const float* __restrict__ dre, const float* __restrict__ dim_,
    const float2* __restrict__ wsv, float2* __restrict__ out) {
  __shared__ float2 wl[C_][F_];
  int blk = blockIdx.x;
  int b = blk / 125;
  int t0 = (blk - b * 125) * 8;
  int tid = threadIdx.x;
  // wsv layout [b][f][c] -> wl[c][f]
  for (int i = tid; i < C_ * F_; i += 256) {
    int f = i >> 3, c = i & 7;
    wl[c][f] = wsv[(size_t)b * (F_ * C_) + i];
  }
  __syncthreads();

  for (int dt = 0; dt < 8; ++dt) {
    int t = t0 + dt;
    const float* pr = dre + (size_t)(b * T_ + t) * (C_ * F_);
    const float* pi_ = dim_ + (size_t)(b * T_ + t) * (C_ * F_);
    for (int f = tid; f < F_; f += 256) {
      float ar = 0.f, ai = 0.f;
#pragma unroll
      for (int c = 0; c < C_; ++c) {
        float xr = pr[c * F_ + f], xi = pi_[c * F_ + f];
        float2 w = wl[c][f];
        ar += w.x * xr + w.y * xi;   // conj(w)*x
        ai += w.x * xi - w.y * xr;
      }
      out[(size_t)(b * T_ + t) * F_ + f] = make_float2(ar, ai);
    }
  }
}

extern "C" void kernel_launch(void* const* d_in, const int* in_sizes, int n_in,
                              void* d_out, int out_size, void* d_ws, size_t ws_size,
                              hipStream_t stream) {
  const float* dre = (const float*)d_in[0];
  const float* dim_ = (const float*)d_in[1];
  const float* ms = (const float*)d_in[2];
  const float* mn = (const float*)d_in[3];
  const float* wmlp = (const float*)d_in[4];
  const float* bmlp = (const float*)d_in[5];
  const float* wgv = (const float*)d_in[6];
  // d_in[7] = b_gvec: constant shift, cancels in softmax — unused.

  char* ws = (char*)d_ws;
  float2* xt   = (float2*)(ws);                 // 131,584,000 B
  float2* psp  = (float2*)(ws + 131584000);     // 4112*64*8 = 2,105,344 B
  float2* pnp  = (float2*)(ws + 133689344);     // 2,105,344 B
  float*  msum = (float*) (ws + 135794688);     // 131,584 B
  float*  nsum = (float*) (ws + 135926272);     // 131,584 B
  float*  feat = (float*) (ws + 136057856);     // 65,792 B
  float*  e_prt= (float*) (ws + 136123648);     // 1,280 B
  float2* wsv  = (float2*)(ws + 136124928);     // 131,584 B
                                                // end: 136,256,512 B

  dim3 g1(9, 32, B_ * C_), b1(32, 8, 1);
  k_transpose<<<g1, b1, 0, stream>>>(dre, dim_, xt);
  k_psd<<<1028, 256, 0, stream>>>(xt, ms, mn, psp, pnp, msum, nsum);
  k_comb<<<B_ * F_, 64, 0, stream>>>(psp, msum, feat);
  dim3 ga(B_, 5, 1);
  k_attn<<<ga, 64, 0, stream>>>(feat, wmlp, bmlp, wgv, e_prt);
  k_solve<<<B_ * F_, 64, 0, stream>>>(psp, pnp, msum, nsum, e_prt, wsv);
  k_bf<<<B_ * 125, 256, 0, stream>>>(dre, dim_, wsv, (float2*)d_out);
}